// Round 8
// baseline (3090.307 us; speedup 1.0000x reference)
//
#include <hip/hip_runtime.h>
#include <hip/hip_bf16.h>

static constexpr int H_ = 1024;
static constexpr int W_ = 1024;
static constexpr int STR_ = 16;
static constexpr int NH_ = 63;
static constexpr int NPATCH_ = NH_ * NH_;  // 3969
static constexpr int HO_ = 1017;           // full-image h1 extent (1024-8+1)

typedef short bf16x8 __attribute__((ext_vector_type(8)));
typedef short short4v __attribute__((ext_vector_type(4)));
typedef float f32x4 __attribute__((ext_vector_type(4)));

// ws layout (both paths): w1frag @0 (8192B) | w2frag @8192 (102400B) |
//                         dw2frag @110592 (102400B) | h1full @212992 (Path A only)
static constexpr size_t WS_FRAGS   = 212992;
static constexpr int    H1_XSTRIDE = 48;                  // bytes (24 bf16 ch)
static constexpr int    H1_YSTRIDE = 1024 * 48;           // 49152
static constexpr size_t H1_BYTES   = (size_t)HO_ * H1_YSTRIDE;  // 49,987,584
static constexpr size_t WS_NEED_A  = WS_FRAGS + H1_BYTES;       // 50,200,576

__device__ __forceinline__ unsigned short f2bf(float x) {
    __hip_bfloat16 b = __float2bfloat16(x);
    return __builtin_bit_cast(unsigned short, b);
}
__device__ __forceinline__ f32x4 mfma_bf16(bf16x8 a, bf16x8 b, f32x4 c) {
    return __builtin_amdgcn_mfma_f32_16x16x32_bf16(a, b, c, 0, 0, 0);
}

// ===========================================================================
// PATH A kernels
// ===========================================================================

// K0: full-image conv1 + ELU -> h1full bf16 [y][x][24ch] (x over 1024 cols).
__global__ __launch_bounds__(512, 4) void conv1_full_kernel(
    const float* __restrict__ x1, const float* __restrict__ x2,
    const float* __restrict__ c1b,
    const unsigned short* __restrict__ w1frag,
    unsigned short* __restrict__ h1full)
{
    __shared__ alignas(16) unsigned short spb[2 * 2 * 39 * 40];  // copy0, copy1
    unsigned short* copy0 = spb;
    unsigned short* copy1 = spb + 2 * 39 * 40;

    const int b  = blockIdx.x;
    const int by = b >> 5, bx = b & 31;
    const int y0 = by * 32, x0 = bx * 32;
    const int t  = (int)threadIdx.x;
    const int wv = t >> 6, lane = t & 63;
    const int ln15 = lane & 15, quad = lane >> 4;

    for (int k = t; k < 2 * 39 * 39; k += 512) {
        int d = k / 1521, r = k % 1521, yy = r / 39, xx = r % 39;
        int gy = y0 + yy; if (gy > 1023) gy = 1023;
        int gx = x0 + xx; if (gx > 1023) gx = 1023;
        unsigned short v = f2bf((d ? x2 : x1)[gy * W_ + gx]);
        int row = (d * 39 + yy) * 40;
        copy0[row + xx] = v;
        if (xx > 0) copy1[row + xx - 1] = v;
    }
    __syncthreads();

    bf16x8 bw[4][2];
    #pragma unroll
    for (int kc = 0; kc < 4; ++kc)
        #pragma unroll
        for (int nt = 0; nt < 2; ++nt)
            bw[kc][nt] = *(const bf16x8*)(w1frag + (((kc * 2 + nt) * 64) + lane) * 8);

    for (int tl = wv; tl < 64; tl += 8) {
        const int vcol = tl >> 1, ubase = (tl & 1) * 16;
        const int u = ubase + ln15;
        const char* abase = (const char*)((vcol & 1) ? copy1 : copy0) + (vcol & ~1) * 2;
        f32x4 acc[2];
        acc[0] = (f32x4){0.f, 0.f, 0.f, 0.f};
        acc[1] = (f32x4){0.f, 0.f, 0.f, 0.f};
        #pragma unroll
        for (int kc = 0; kc < 4; ++kc) {
            const int idx8 = kc * 4 + quad;               // k/8 = d*8+p
            const int dd = idx8 >> 3, pp = idx8 & 7;
            const unsigned int* ap = (const unsigned int*)(abase + (dd * 39 + u + pp) * 80);
            union { unsigned int u4[4]; bf16x8 v; } af;
            af.u4[0] = ap[0]; af.u4[1] = ap[1]; af.u4[2] = ap[2]; af.u4[3] = ap[3];
            acc[0] = mfma_bf16(af.v, bw[kc][0], acc[0]);
            acc[1] = mfma_bf16(af.v, bw[kc][1], acc[1]);
        }
        const int xg = x0 + vcol;
        #pragma unroll
        for (int ntp = 0; ntp < 2; ++ntp) {
            const int c = ntp * 16 + ln15;
            if (c < 24) {
                const float bias = c1b[c];
                #pragma unroll
                for (int r = 0; r < 4; ++r) {
                    int yg = y0 + ubase + quad * 4 + r;
                    if (yg < HO_ && xg < HO_) {
                        float hv = acc[ntp][r] + bias;
                        hv = hv > 0.f ? hv : expm1f(hv);
                        h1full[(yg * 1024 + xg) * 24 + c] = f2bf(hv);
                    }
                }
            }
        }
    }
}

// Path A fused LDS (61248 B -> 2 blocks/CU):
//   sH2  [0,52920): 441 x 120B ([pixel][60ch bf16]); h3 overlays [0,30000) after
//   zrow [52920,53056): 136B zero row
//   sWc  [53056,57152): 64 rows x 64B bf16  (4096B — R6/R7 bug: only 2048 reserved)
//   sp   [57152,61248): 32x32 f32 accumulator
static constexpr int A_SH2_STRIDE = 120;
static constexpr int A_ZROW  = 52920;
static constexpr int A_SWC   = 53056;
static constexpr int A_SP    = 57152;
static constexpr int A_LDS   = 61248;
static constexpr int A_H3STR = 48;

__global__ __launch_bounds__(512, 4) void fused_patch_global(
    const float* __restrict__ c2b, const float* __restrict__ d2b,
    const float* __restrict__ d1b,
    const float* __restrict__ lin_w, const float* __restrict__ lin_b,
    const unsigned short* __restrict__ h1full,
    const unsigned short* __restrict__ w2frag,
    const unsigned short* __restrict__ dw2frag,
    const float* __restrict__ dw1,
    float* __restrict__ recon)
{
    __shared__ alignas(16) char sbuf[A_LDS];
    const int n  = blockIdx.x;
    const int t  = (int)threadIdx.x;
    const int pi = n / NH_, pj = n % NH_;
    const int Y0 = pi * STR_, X0 = pj * STR_;
    const int wv = t >> 6, lane = t & 63;
    const int ln15 = lane & 15, quad = lane >> 4;

    if (t < 34) ((float*)(sbuf + A_ZROW))[t] = 0.f;   // covered by post-conv2 barrier

    // conv2: M=441(->448), N=64 (60+4 pad), K=32 (24+8 garbage x B-zeros)
    float bias2[4];
    #pragma unroll
    for (int nt = 0; nt < 4; ++nt) {
        int o = nt * 16 + ln15;
        bias2[nt] = (o < 60) ? c2b[o] : 0.f;
    }
    for (int mt = wv; mt < 28; mt += 8) {
        int m = mt * 16 + ln15;
        if (m > 440) m = 440;
        int hy = m / 21, hx = m % 21;
        const char* abase = (const char*)h1full
                          + ((Y0 + hy) * 1024 + (X0 + hx)) * H1_XSTRIDE + quad * 16;
        f32x4 acc[4];
        #pragma unroll
        for (int nt = 0; nt < 4; ++nt) acc[nt] = (f32x4){0.f, 0.f, 0.f, 0.f};
        const unsigned short* wb = w2frag + lane * 8;
        #pragma unroll
        for (int p = 0; p < 5; ++p) {
            #pragma unroll
            for (int q = 0; q < 5; ++q) {
                const int tap = p * 5 + q;
                bf16x8 a = *(const bf16x8*)(abase + p * H1_YSTRIDE + q * H1_XSTRIDE);
                #pragma unroll
                for (int nt = 0; nt < 4; ++nt) {
                    bf16x8 bb = *(const bf16x8*)(wb + (tap * 4 + nt) * 512);
                    acc[nt] = mfma_bf16(a, bb, acc[nt]);
                }
            }
        }
        #pragma unroll
        for (int r = 0; r < 4; ++r) {
            int pix = mt * 16 + quad * 4 + r;
            if (pix < 441) {
                unsigned short* rowp = (unsigned short*)(sbuf + pix * A_SH2_STRIDE);
                #pragma unroll
                for (int nt = 0; nt < 4; ++nt) {
                    int o = nt * 16 + ln15;
                    if (o < 60)
                        rowp[o] = f2bf(fmaxf(acc[nt][r] + bias2[nt], 0.f));
                }
            }
        }
    }
    __syncthreads();

    // deconv2: M=625(->640, 40 mtiles), N=32 (24+8), K=64 (60+4 B-zero), 25 taps
    f32x4 acc3[5][2];
    {
        int uarr[5], varr[5], a120[5];
        bool mval[5];
        #pragma unroll
        for (int i = 0; i < 5; ++i) {
            acc3[i][0] = (f32x4){0.f, 0.f, 0.f, 0.f};
            acc3[i][1] = (f32x4){0.f, 0.f, 0.f, 0.f};
            int m = (wv + i * 8) * 16 + ln15;
            mval[i] = (m < 625);
            int mc = mval[i] ? m : 0;
            uarr[i] = mc / 25; varr[i] = mc % 25;
            a120[i] = (uarr[i] * 21 + varr[i]) * A_SH2_STRIDE;
        }
        const unsigned short* db = dw2frag + lane * 8;
        #pragma unroll
        for (int dy = 0; dy < 5; ++dy) {
            #pragma unroll
            for (int dx = 0; dx < 5; ++dx) {
                const int tap   = dy * 5 + dx;
                const int t2off = (dy * 21 + dx) * A_SH2_STRIDE;
                bf16x8 b00 = *(const bf16x8*)(db + tap * 2048);
                bf16x8 b01 = *(const bf16x8*)(db + tap * 2048 + 512);
                bf16x8 b10 = *(const bf16x8*)(db + tap * 2048 + 1024);
                bf16x8 b11 = *(const bf16x8*)(db + tap * 2048 + 1536);
                #pragma unroll
                for (int i = 0; i < 5; ++i) {
                    int yv = uarr[i] - dy, xv = varr[i] - dx;
                    bool ok = mval[i] && ((unsigned)yv < 21u) && ((unsigned)xv < 21u);
                    int ra = ok ? (a120[i] - t2off) : A_ZROW;
                    const char* ap = sbuf + ra + quad * 16;
                    short4v lo0 = *(const short4v*)(ap);
                    short4v hi0 = *(const short4v*)(ap + 8);
                    bf16x8 a0 = __builtin_shufflevector(lo0, hi0, 0, 1, 2, 3, 4, 5, 6, 7);
                    acc3[i][0] = mfma_bf16(a0, b00, acc3[i][0]);
                    acc3[i][1] = mfma_bf16(a0, b01, acc3[i][1]);
                    short4v lo1 = *(const short4v*)(ap + 64);
                    short4v hi1 = *(const short4v*)(ap + 72);
                    bf16x8 a1 = __builtin_shufflevector(lo1, hi1, 0, 1, 2, 3, 4, 5, 6, 7);
                    acc3[i][0] = mfma_bf16(a1, b10, acc3[i][0]);
                    acc3[i][1] = mfma_bf16(a1, b11, acc3[i][1]);
                }
            }
        }
    }
    __syncthreads();   // sH2 dead

    const float lw0 = lin_w[2 * n], lw1 = lin_w[2 * n + 1];
    float* sp = (float*)(sbuf + A_SP);
    {
        const int c0 = ln15, c1 = 16 + ln15;
        const float db0 = d2b[c0];
        const float db1 = (c1 < 24) ? d2b[c1] : 0.f;
        #pragma unroll
        for (int i = 0; i < 5; ++i) {
            #pragma unroll
            for (int r = 0; r < 4; ++r) {
                int pix = (wv + i * 8) * 16 + quad * 4 + r;
                if (pix < 625) {
                    unsigned short* rowp = (unsigned short*)(sbuf + pix * A_H3STR);
                    float hv = acc3[i][0][r] + db0;
                    rowp[c0] = f2bf(hv > 0.f ? hv : expm1f(hv));
                    if (c1 < 24) {
                        float hw = acc3[i][1][r] + db1;
                        rowp[c1] = f2bf(hw > 0.f ? hw : expm1f(hw));
                    }
                }
            }
        }
    }
    for (int k = t; k < 2048; k += 512) {   // sWc: 64 r x 32 c bf16 = 4096 B
        int r = k >> 5, c = k & 31;
        float v = 0.f;
        if (c < 24)
            v = lw0 * dw1[(c * 2 + 0) * 64 + r] + lw1 * dw1[(c * 2 + 1) * 64 + r];
        ((unsigned short*)(sbuf + A_SWC))[r * 32 + c] = f2bf(v);
    }
    for (int k = t; k < 1024; k += 512) sp[k] = 0.f;
    __syncthreads();

    {
        bf16x8 wbv[4];
        #pragma unroll
        for (int nt = 0; nt < 4; ++nt)
            wbv[nt] = *(const bf16x8*)(sbuf + A_SWC + (nt * 16 + ln15) * 64 + quad * 16);
        #pragma unroll
        for (int i = 0; i < 5; ++i) {
            int mt = wv + i * 8;
            int m = mt * 16 + ln15;
            if (m > 624) m = 624;
            bf16x8 a = *(const bf16x8*)(sbuf + m * A_H3STR + quad * 16);
            #pragma unroll
            for (int nt = 0; nt < 4; ++nt) {
                f32x4 acc4 = (f32x4){0.f, 0.f, 0.f, 0.f};
                acc4 = mfma_bf16(a, wbv[nt], acc4);
                #pragma unroll
                for (int r = 0; r < 4; ++r) {
                    int pix = mt * 16 + quad * 4 + r;
                    if (pix < 625) {
                        int u = pix / 25, v = pix % 25;
                        int rv = nt * 16 + ln15;
                        atomicAdd(&sp[(u + (rv >> 3)) * 32 + v + (rv & 7)], acc4[r]);
                    }
                }
            }
        }
    }
    __syncthreads();

    const float obias = d1b[0] * (lw0 + lw1) + lin_b[n];
    for (int k = t; k < 1024; k += 512) {
        int yy = k >> 5, xx = k & 31;
        atomicAdd(&recon[(Y0 + yy) * W_ + (X0 + xx)], sp[k] + obias);
    }
}

// ===========================================================================
// PATH B kernel — verbatim R5 (passed @1435us); used when ws_size < WS_NEED_A
// ===========================================================================
static constexpr int B_SH1_STRIDE = 48;
static constexpr int B_SH2_BASE   = 30016;
static constexpr int B_SH2_STRIDE = 120;
static constexpr int B_ZROW_REL   = 441 * B_SH2_STRIDE;
static constexpr int B_SPB0       = 30016;
static constexpr int B_SPB1       = 35136;
static constexpr int B_SWC_BASE   = 30016;
static constexpr int B_SP_ACC     = 34112;
static constexpr int B_LDS_BYTES  = 83072;

__global__ __launch_bounds__(1024, 4) void fused_patch_local(
    const float* __restrict__ x1, const float* __restrict__ x2,
    const float* __restrict__ c1b, const float* __restrict__ c2b,
    const float* __restrict__ d2b, const float* __restrict__ d1b,
    const float* __restrict__ lin_w, const float* __restrict__ lin_b,
    const unsigned short* __restrict__ w1frag,
    const unsigned short* __restrict__ w2frag,
    const unsigned short* __restrict__ dw2frag,
    const float* __restrict__ dw1,
    float* __restrict__ recon)
{
    __shared__ alignas(16) char sbuf[B_LDS_BYTES];
    const int n  = blockIdx.x;
    const int t  = (int)threadIdx.x;
    const int pi = n / NH_, pj = n % NH_;
    const int Y0 = pi * STR_, X0 = pj * STR_;
    const int wv = t >> 6, lane = t & 63;
    const int ln15 = lane & 15, quad = lane >> 4;

    if (t < 30) ((float*)(sbuf + B_SH2_BASE + B_ZROW_REL))[t] = 0.f;
    for (int k = t; k < 2048; k += 1024) {
        int d = k >> 10, r = k & 1023, y = r >> 5, x = r & 31;
        unsigned short b = f2bf((d ? x2 : x1)[(Y0 + y) * W_ + (X0 + x)]);
        int row = (d * 32 + y) * 40;
        ((unsigned short*)(sbuf + B_SPB0))[row + x] = b;
        if (x > 0) ((unsigned short*)(sbuf + B_SPB1))[row + x - 1] = b;
    }
    __syncthreads();

    for (int tl = wv; tl < 50; tl += 16) {
        const int vcol = tl >> 1, ubase = (tl & 1) * 16;
        const int u = ubase + ln15;
        const char* abase = sbuf + ((vcol & 1) ? B_SPB1 : B_SPB0) + (vcol & ~1) * 2;
        f32x4 acc[2];
        acc[0] = (f32x4){0.f, 0.f, 0.f, 0.f};
        acc[1] = (f32x4){0.f, 0.f, 0.f, 0.f};
        #pragma unroll
        for (int kc = 0; kc < 4; ++kc) {
            const int idx8 = kc * 4 + quad;
            const int dd = idx8 >> 3, pp = idx8 & 7;
            const unsigned int* ap = (const unsigned int*)(abase + (dd * 32 + u + pp) * 80);
            union { unsigned int u4[4]; bf16x8 v; } af;
            af.u4[0] = ap[0]; af.u4[1] = ap[1]; af.u4[2] = ap[2]; af.u4[3] = ap[3];
            bf16x8 b0 = *(const bf16x8*)(w1frag + (((kc * 2 + 0) * 64) + lane) * 8);
            bf16x8 b1 = *(const bf16x8*)(w1frag + (((kc * 2 + 1) * 64) + lane) * 8);
            acc[0] = mfma_bf16(af.v, b0, acc[0]);
            acc[1] = mfma_bf16(af.v, b1, acc[1]);
        }
        #pragma unroll
        for (int ntp = 0; ntp < 2; ++ntp) {
            const int c = ntp * 16 + ln15;
            if (c < 24) {
                const float bias = c1b[c];
                #pragma unroll
                for (int r = 0; r < 4; ++r) {
                    int uu = ubase + quad * 4 + r;
                    if (uu < 25) {
                        float hv = acc[ntp][r] + bias;
                        hv = hv > 0.f ? hv : expm1f(hv);
                        *(unsigned short*)(sbuf + (uu * 25 + vcol) * B_SH1_STRIDE + c * 2) = f2bf(hv);
                    }
                }
            }
        }
    }
    __syncthreads();

    if (wv < 14) {
        int abase2[2];
        #pragma unroll
        for (int i = 0; i < 2; ++i) {
            int m = (wv + i * 14) * 16 + ln15;
            if (m > 440) m = 440;
            abase2[i] = ((m / 21) * 25 + (m % 21)) * B_SH1_STRIDE;
        }
        float bias[4];
        #pragma unroll
        for (int nt = 0; nt < 4; ++nt) {
            int o = nt * 16 + ln15;
            bias[nt] = (o < 60) ? c2b[o] : 0.f;
        }
        f32x4 acc2[2][4];
        #pragma unroll
        for (int i = 0; i < 2; ++i)
            #pragma unroll
            for (int nt = 0; nt < 4; ++nt)
                acc2[i][nt] = (f32x4){0.f, 0.f, 0.f, 0.f};

        const unsigned short* wb = w2frag + lane * 8;
        #pragma unroll
        for (int p = 0; p < 5; ++p) {
            #pragma unroll
            for (int q = 0; q < 5; ++q) {
                const int tap  = p * 5 + q;
                const int toff = (p * 25 + q) * B_SH1_STRIDE;
                bf16x8 b[4];
                #pragma unroll
                for (int nt = 0; nt < 4; ++nt)
                    b[nt] = *(const bf16x8*)(wb + (tap * 4 + nt) * 512);
                #pragma unroll
                for (int i = 0; i < 2; ++i) {
                    bf16x8 a = *(const bf16x8*)(sbuf + abase2[i] + toff + quad * 16);
                    #pragma unroll
                    for (int nt = 0; nt < 4; ++nt)
                        acc2[i][nt] = mfma_bf16(a, b[nt], acc2[i][nt]);
                }
            }
        }
        #pragma unroll
        for (int i = 0; i < 2; ++i) {
            #pragma unroll
            for (int r = 0; r < 4; ++r) {
                int pix = (wv + i * 14) * 16 + quad * 4 + r;
                if (pix < 441) {
                    unsigned short* rowp = (unsigned short*)(sbuf + B_SH2_BASE + pix * B_SH2_STRIDE);
                    #pragma unroll
                    for (int nt = 0; nt < 4; ++nt) {
                        int o = nt * 16 + ln15;
                        if (o < 60)
                            rowp[o] = f2bf(fmaxf(acc2[i][nt][r] + bias[nt], 0.f));
                    }
                }
            }
        }
    }
    __syncthreads();

    f32x4 acc3[3][2];
    {
        #pragma unroll
        for (int i = 0; i < 3; ++i) {
            acc3[i][0] = (f32x4){0.f, 0.f, 0.f, 0.f};
            acc3[i][1] = (f32x4){0.f, 0.f, 0.f, 0.f};
        }
        int uarr[3], varr[3], a120[3];
        bool mval[3];
        #pragma unroll
        for (int i = 0; i < 3; ++i) {
            int m = (wv + i * 16) * 16 + ln15;
            mval[i] = (m < 625);
            int mc = mval[i] ? m : 0;
            uarr[i] = mc / 25; varr[i] = mc % 25;
            a120[i] = (uarr[i] * 21 + varr[i]) * B_SH2_STRIDE;
        }
        const unsigned short* db = dw2frag + lane * 8;
        #pragma unroll
        for (int dy = 0; dy < 5; ++dy) {
            #pragma unroll
            for (int dx = 0; dx < 5; ++dx) {
                const int tap   = dy * 5 + dx;
                const int t2off = (dy * 21 + dx) * B_SH2_STRIDE;
                bf16x8 b00 = *(const bf16x8*)(db + tap * 2048);
                bf16x8 b01 = *(const bf16x8*)(db + tap * 2048 + 512);
                bf16x8 b10 = *(const bf16x8*)(db + tap * 2048 + 1024);
                bf16x8 b11 = *(const bf16x8*)(db + tap * 2048 + 1536);
                #pragma unroll
                for (int i = 0; i < 3; ++i) {
                    if (i == 2 && wv >= 8) continue;
                    int yv = uarr[i] - dy, xv = varr[i] - dx;
                    bool ok = mval[i] && ((unsigned)yv < 21u) && ((unsigned)xv < 21u);
                    int ra = ok ? (a120[i] - t2off) : B_ZROW_REL;
                    const char* ap = sbuf + B_SH2_BASE + ra + quad * 16;
                    short4v lo0 = *(const short4v*)(ap);
                    short4v hi0 = *(const short4v*)(ap + 8);
                    bf16x8 a0 = __builtin_shufflevector(lo0, hi0, 0, 1, 2, 3, 4, 5, 6, 7);
                    acc3[i][0] = mfma_bf16(a0, b00, acc3[i][0]);
                    acc3[i][1] = mfma_bf16(a0, b01, acc3[i][1]);
                    short4v lo1 = *(const short4v*)(ap + 64);
                    short4v hi1 = *(const short4v*)(ap + 72);
                    bf16x8 a1 = __builtin_shufflevector(lo1, hi1, 0, 1, 2, 3, 4, 5, 6, 7);
                    acc3[i][0] = mfma_bf16(a1, b10, acc3[i][0]);
                    acc3[i][1] = mfma_bf16(a1, b11, acc3[i][1]);
                }
            }
        }
    }
    __syncthreads();

    const float lw0 = lin_w[2 * n], lw1 = lin_w[2 * n + 1];
    float* sp = (float*)(sbuf + B_SP_ACC);
    {
        const int c0 = ln15, c1 = 16 + ln15;
        const float db0 = d2b[c0];
        const float db1 = (c1 < 24) ? d2b[c1] : 0.f;
        #pragma unroll
        for (int i = 0; i < 3; ++i) {
            if (i == 2 && wv >= 8) continue;
            #pragma unroll
            for (int r = 0; r < 4; ++r) {
                int pix = (wv + i * 16) * 16 + quad * 4 + r;
                if (pix < 625) {
                    unsigned short* rowp = (unsigned short*)(sbuf + pix * B_SH1_STRIDE);
                    float hv = acc3[i][0][r] + db0;
                    rowp[c0] = f2bf(hv > 0.f ? hv : expm1f(hv));
                    if (c1 < 24) {
                        float hw = acc3[i][1][r] + db1;
                        rowp[c1] = f2bf(hw > 0.f ? hw : expm1f(hw));
                    }
                }
            }
        }
    }
    for (int k = t; k < 2048; k += 1024) {
        int r = k >> 5, c = k & 31;
        float v = 0.f;
        if (c < 24)
            v = lw0 * dw1[(c * 2 + 0) * 64 + r] + lw1 * dw1[(c * 2 + 1) * 64 + r];
        ((unsigned short*)(sbuf + B_SWC_BASE))[r * 32 + c] = f2bf(v);
    }
    sp[t] = 0.f;
    __syncthreads();

    {
        bf16x8 wbv[4];
        #pragma unroll
        for (int nt = 0; nt < 4; ++nt)
            wbv[nt] = *(const bf16x8*)(sbuf + B_SWC_BASE + (nt * 16 + ln15) * 64 + quad * 16);
        #pragma unroll
        for (int i = 0; i < 3; ++i) {
            int mt = wv + i * 16;
            if (mt >= 40) continue;
            int m = mt * 16 + ln15;
            if (m > 624) m = 624;
            bf16x8 a = *(const bf16x8*)(sbuf + m * B_SH1_STRIDE + quad * 16);
            #pragma unroll
            for (int nt = 0; nt < 4; ++nt) {
                f32x4 acc4 = (f32x4){0.f, 0.f, 0.f, 0.f};
                acc4 = mfma_bf16(a, wbv[nt], acc4);
                #pragma unroll
                for (int r = 0; r < 4; ++r) {
                    int pix = mt * 16 + quad * 4 + r;
                    if (pix < 625) {
                        int u = pix / 25, v = pix % 25;
                        int rv = nt * 16 + ln15;
                        atomicAdd(&sp[(u + (rv >> 3)) * 32 + v + (rv & 7)], acc4[r]);
                    }
                }
            }
        }
    }
    __syncthreads();

    const float obias = d1b[0] * (lw0 + lw1) + lin_b[n];
    {
        int yy = t >> 5, xx = t & 31;
        atomicAdd(&recon[(Y0 + yy) * W_ + (X0 + xx)], sp[t] + obias);
    }
}

// ===========================================================================
// Shared prep / finalize
// ===========================================================================
__global__ void prep_kernel(const float* __restrict__ c1w,
                            const float* __restrict__ c2w,
                            const float* __restrict__ d2w,
                            unsigned short* __restrict__ w1frag,
                            unsigned short* __restrict__ w2frag,
                            unsigned short* __restrict__ dw2frag)
{
    int i = blockIdx.x * blockDim.x + threadIdx.x;
    if (i < 51200) {
        int j = i & 7, lane = (i >> 3) & 63;
        int ln15 = lane & 15, quad = lane >> 4;
        if (i < 4096) {   // conv1
            int g = i >> 9;
            int kc = g >> 1, nt = g & 1;
            int nn = nt * 16 + ln15, k = kc * 32 + quad * 8 + j;
            w1frag[i] = f2bf((nn < 24) ? c1w[nn * 128 + k] : 0.f);
        }
        {   // conv2
            int nt = (i >> 9) & 3, tap = i >> 11;
            int o = nt * 16 + ln15, c = quad * 8 + j;
            float v = (o < 60 && c < 24) ? c2w[(o * 24 + c) * 25 + tap] : 0.f;
            w2frag[i] = f2bf(v);
        }
        {   // deconv2
            int nt = (i >> 9) & 1, kc = (i >> 10) & 1, tap = i >> 11;
            int k = kc * 32 + quad * 8 + j, c = nt * 16 + ln15;
            float v = (k < 60 && c < 24) ? d2w[(k * 24 + c) * 25 + tap] : 0.f;
            dw2frag[i] = f2bf(v);
        }
    }
}

__global__ void finalize_kernel(const float* __restrict__ x2,
                                const float* __restrict__ l1w,
                                float* __restrict__ out)
{
    int i = blockIdx.x * blockDim.x + threadIdx.x;
    if (i < H_ * W_) {
        float r = out[i];
        out[i] = x2[i] - r * l1w[0];
    }
}

extern "C" void kernel_launch(void* const* d_in, const int* in_sizes, int n_in,
                              void* d_out, int out_size, void* d_ws, size_t ws_size,
                              hipStream_t stream)
{
    const float* x1  = (const float*)d_in[0];
    const float* x2  = (const float*)d_in[1];
    const float* c1w = (const float*)d_in[2];
    const float* c1b = (const float*)d_in[3];
    const float* c2w = (const float*)d_in[4];
    const float* c2b = (const float*)d_in[5];
    const float* d2w = (const float*)d_in[6];
    const float* d2b = (const float*)d_in[7];
    const float* d1w = (const float*)d_in[8];
    const float* d1b = (const float*)d_in[9];
    const float* lw  = (const float*)d_in[10];
    const float* lb  = (const float*)d_in[11];
    const float* l1w = (const float*)d_in[12];

    float* out = (float*)d_out;
    unsigned short* w1frag  = (unsigned short*)d_ws;
    unsigned short* w2frag  = (unsigned short*)((char*)d_ws + 8192);
    unsigned short* dw2frag = (unsigned short*)((char*)d_ws + 110592);
    unsigned short* h1full  = (unsigned short*)((char*)d_ws + WS_FRAGS);

    hipMemsetAsync(d_out, 0, (size_t)H_ * W_ * sizeof(float), stream);
    prep_kernel<<<100, 512, 0, stream>>>(c1w, c2w, d2w, w1frag, w2frag, dw2frag);

    if (ws_size >= WS_NEED_A) {
        conv1_full_kernel<<<1024, 512, 0, stream>>>(x1, x2, c1b, w1frag, h1full);
        fused_patch_global<<<NPATCH_, 512, 0, stream>>>(c2b, d2b, d1b, lw, lb,
                                                        h1full, w2frag, dw2frag,
                                                        d1w, out);
    } else {
        fused_patch_local<<<NPATCH_, 1024, 0, stream>>>(x1, x2, c1b, c2b, d2b, d1b,
                                                        lw, lb, w1frag, w2frag, dw2frag,
                                                        d1w, out);
    }
    finalize_kernel<<<(H_ * W_ + 255) / 256, 256, 0, stream>>>(x2, l1w, out);
}